// Round 9
// baseline (607.821 us; speedup 1.0000x reference)
//
#include <hip/hip_runtime.h>
#include <cstdint>

#define FDIM 64
#define KNN 32
#define NBUCKET 256
#define MAXCAP 2048
#define SEG 10
#define OCAP 512

typedef unsigned int u32;
typedef unsigned long long u64;
typedef __attribute__((ext_vector_type(8))) short bf16x8;
typedef __attribute__((ext_vector_type(4))) float f32x4;

// ---- shared fp32 helpers
__device__ __forceinline__ float load_query(const float* __restrict__ x, int q, float4* xv) {
    const float4* xp = (const float4*)(x + (size_t)q * FDIM);
    float n0 = 0.f, n1 = 0.f, n2 = 0.f, n3 = 0.f;
#pragma unroll
    for (int k = 0; k < 16; ++k) {
        float4 v = xp[k];
        xv[k] = v;
        n0 = fmaf(v.x, v.x, n0); n1 = fmaf(v.y, v.y, n1);
        n2 = fmaf(v.z, v.z, n2); n3 = fmaf(v.w, v.w, n3);
    }
    return (n0 + n1) + (n2 + n3);
}

__device__ __forceinline__ float dot_row(const float4* __restrict__ xv, const float* __restrict__ row) {
    const float4* rv = (const float4*)row;
    float d0 = 0.f, d1 = 0.f, d2 = 0.f, d3 = 0.f;
#pragma unroll
    for (int k = 0; k < 16; ++k) {
        float4 r = rv[k];
        float4 a = xv[k];
        d0 = fmaf(a.x, r.x, d0); d1 = fmaf(a.y, r.y, d1);
        d2 = fmaf(a.z, r.z, d2); d3 = fmaf(a.w, r.w, d3);
    }
    return (d0 + d1) + (d2 + d3);
}

// ---- K1: row norms
__global__ __launch_bounds__(256) void k_xnorm(const float* __restrict__ X, float* __restrict__ Xn, int N) {
    int i = blockIdx.x * 256 + threadIdx.x;
    if (i >= N) return;
    const float4* r = (const float4*)(X + (size_t)i * FDIM);
    float d0 = 0.f, d1 = 0.f, d2 = 0.f, d3 = 0.f;
#pragma unroll
    for (int k = 0; k < 16; ++k) {
        float4 v = r[k];
        d0 = fmaf(v.x, v.x, d0); d1 = fmaf(v.y, v.y, d1);
        d2 = fmaf(v.z, v.z, d2); d3 = fmaf(v.w, v.w, d3);
    }
    Xn[i] = (d0 + d1) + (d2 + d3);
}

// ---- K1b: fused fp32->bf16 (RNE) + transpose into MFMA-fragment order.
__global__ __launch_bounds__(256) void k_cvtT(const float* __restrict__ src, uint4* __restrict__ dst, int n_u4) {
    int i = blockIdx.x * 256 + threadIdx.x;
    if (i >= n_u4) return;
    int lane = i & 63;
    int kk = (i >> 6) & 1;
    int g = i >> 7;
    int row = g * 16 + (lane & 15);
    int col = kk * 32 + (lane >> 4) * 8;
    const float4* s = (const float4*)(src + (size_t)row * FDIM + col);
    float4 a = s[0], b = s[1];
    ushort o[8];
    const float* f = &a.x;
#pragma unroll
    for (int k = 0; k < 4; ++k) {
        u32 u = __float_as_uint(f[k]);
        o[k] = (ushort)((u + 0x7fffu + ((u >> 16) & 1u)) >> 16);
    }
    const float* gg = &b.x;
#pragma unroll
    for (int k = 0; k < 4; ++k) {
        u32 u = __float_as_uint(gg[k]);
        o[4 + k] = (ushort)((u + 0x7fffu + ((u >> 16) & 1u)) >> 16);
    }
    dst[i] = *(uint4*)o;
}

// ---- legacy scalar sample-hist kernels (fallback when ws is tight) ----
__global__ __launch_bounds__(256) void k_hist(const float* __restrict__ x, const float* __restrict__ X,
                                              const float* __restrict__ Xn, u32* __restrict__ hist,
                                              int N, int nsamp, int sj) {
    __shared__ unsigned char h8[NBUCKET * 256];
    int t = threadIdx.x;
    u32* h32 = (u32*)h8;
#pragma unroll
    for (int k = 0; k < 64; ++k) h32[k * 256 + t] = 0;
    __syncthreads();
    int q = blockIdx.x * 256 + t;
    float4 xv[16];
    float xn = load_query(x, q, xv);
    for (int j = 0; j < sj; ++j) {
        int s = blockIdx.y * sj + j;
        int p = s * 16;
        if (s < nsamp && p < N) {
            float dp = dot_row(xv, X + (size_t)p * FDIM);
            float d2 = fmaxf(xn + Xn[p] - 2.f * dp, 0.f);
            int b = min(NBUCKET - 1, (int)d2);
            int idx = b * 256 + t;
            unsigned char v = h8[idx];
            h8[idx] = (v == 255u) ? v : (unsigned char)(v + 1);
        }
    }
    __syncthreads();
#pragma unroll
    for (int w = 0; w < 128; ++w) {
        u32 v0 = h8[(2 * w) * 256 + t];
        u32 v1 = h8[(2 * w + 1) * 256 + t];
        if (v0 | v1) atomicAdd(&hist[(size_t)q * 128 + w], v0 | (v1 << 16));
    }
}

__global__ __launch_bounds__(256) void k_thresh(const u32* __restrict__ hist, float* __restrict__ Tq, int B) {
    int q = blockIdx.x * 256 + threadIdx.x;
    if (q >= B) return;
    const u32* h = hist + (size_t)q * 128;
    int cum = 0;
    float T = (float)NBUCKET;
    for (int w = 0; w < 128; ++w) {
        u32 v = h[w];
        cum += (int)(v & 0xffffu);
        if (cum >= KNN) { T = (float)(2 * w + 1); break; }
        cum += (int)(v >> 16);
        if (cum >= KNN) { T = (float)(2 * w + 2); break; }
    }
    Tq[q] = T + 2.0f;
}

// ---- K2 (MFMA sample pass): d2a buckets for the first S=Stiles*128 rows.
__global__ __launch_bounds__(256, 3) void k_sample_d2(
        const uint4* __restrict__ xT, const uint4* __restrict__ XT,
        const float* __restrict__ qn, const float* __restrict__ Xn,
        unsigned char* __restrict__ d2s, int S) {
    int t = threadIdx.x;
    int w = t >> 6, lane = t & 63;
    int G = lane >> 4, r = lane & 15;
    int qg = blockIdx.x;
    int wq = qg * 128 + w * 32;
    int pb = blockIdx.y * 128;

    bf16x8 afr[2][2];
#pragma unroll
    for (int kk = 0; kk < 2; ++kk)
#pragma unroll
        for (int mi = 0; mi < 2; ++mi) {
            uint4 v = xT[(size_t)(((wq >> 4) + mi) * 2 + kk) * 64 + lane];
            afr[kk][mi] = *(bf16x8*)&v;
        }
    float qr[8];
#pragma unroll
    for (int e = 0; e < 8; ++e)
        qr[e] = qn[wq + (e >> 2) * 16 + G * 4 + (e & 3)];

#pragma unroll
    for (int half = 0; half < 2; ++half) {
        int nb = half * 4;
        bf16x8 bfr[4][2];
#pragma unroll
        for (int j = 0; j < 4; ++j) {
            int gp = (pb >> 4) + nb + j;
#pragma unroll
            for (int kk = 0; kk < 2; ++kk) {
                uint4 v = XT[(size_t)(gp * 2 + kk) * 64 + lane];
                bfr[j][kk] = *(bf16x8*)&v;
            }
        }
        float xnv[4];
#pragma unroll
        for (int j = 0; j < 4; ++j) xnv[j] = Xn[pb + (nb + j) * 16 + r];

        f32x4 acc[2][4];
#pragma unroll
        for (int mi = 0; mi < 2; ++mi)
#pragma unroll
            for (int j = 0; j < 4; ++j) acc[mi][j] = (f32x4){0.f, 0.f, 0.f, 0.f};
#pragma unroll
        for (int kk = 0; kk < 2; ++kk)
#pragma unroll
            for (int j = 0; j < 4; ++j) {
                acc[0][j] = __builtin_amdgcn_mfma_f32_16x16x32_bf16(afr[kk][0], bfr[j][kk], acc[0][j], 0, 0, 0);
                acc[1][j] = __builtin_amdgcn_mfma_f32_16x16x32_bf16(afr[kk][1], bfr[j][kk], acc[1][j], 0, 0, 0);
            }
#pragma unroll
        for (int j = 0; j < 4; ++j) {
            int p = pb + (nb + j) * 16 + r;
            float xnp = xnv[j];
#pragma unroll
            for (int e = 0; e < 8; ++e) {
                float d2a = qr[e] + fmaf(-2.f, acc[e >> 2][j][e & 3], xnp);
                int b = (int)d2a;
                b = b < 0 ? 0 : (b > 255 ? 255 : b);
                int q = wq + (e >> 2) * 16 + G * 4 + (e & 3);
                d2s[(size_t)q * S + p] = (unsigned char)b;
            }
        }
    }
}

// ---- K2b: per-query hist of d2a bytes -> threshold + 2eps margin (eps=1.0)
__global__ __launch_bounds__(256) void k_thresh2(const unsigned char* __restrict__ d2s,
                                                 float* __restrict__ Tq, int S) {
    __shared__ u32 h[NBUCKET];
    int t = threadIdx.x;
    int q = blockIdx.x;
    h[t] = 0;
    __syncthreads();
    const u32* row = (const u32*)(d2s + (size_t)q * S);
    int n4 = S >> 2;
    for (int i = t; i < n4; i += 256) {
        u32 v = row[i];
        atomicAdd(&h[v & 255u], 1u);
        atomicAdd(&h[(v >> 8) & 255u], 1u);
        atomicAdd(&h[(v >> 16) & 255u], 1u);
        atomicAdd(&h[v >> 24], 1u);
    }
    __syncthreads();
    if (t == 0) {
        int cum = 0;
        float T = 256.0f;
        for (int b = 0; b < NBUCKET; ++b) {
            cum += (int)h[b];
            if (cum >= KNN) { T = (float)(b + 1); break; }
        }
        Tq[q] = T + 2.0f;
    }
}

// ---- K3: LDS-free MFMA filter; per-(q,strip) segments via LDS atomics
__global__ __launch_bounds__(256, 3) void k_mfma_filter(
        const uint4* __restrict__ xT, const uint4* __restrict__ XT,
        const float* __restrict__ qn, const float* __restrict__ Xn,
        const float* __restrict__ Tf,
        u32* __restrict__ cnt_seg, u32* __restrict__ list_seg,
        u32* __restrict__ ocnt, u32* __restrict__ olist,
        int N, int nStripsPad, int strip) {
    __shared__ u32 ldsCnt[128];

    int t = threadIdx.x;
    int w = t >> 6, lane = t & 63;
    int G = lane >> 4, r = lane & 15;

    int bid = blockIdx.x;
    int qg = (bid >> 3) & 7;
    int sIdx = (bid & 7) | ((bid >> 6) << 3);
    int qbase = qg * 128;
    int wq = qbase + w * 32;

    if (t < 128) ldsCnt[t] = 0;
    __syncthreads();

    bf16x8 afr[2][2];
#pragma unroll
    for (int kk = 0; kk < 2; ++kk)
#pragma unroll
        for (int mi = 0; mi < 2; ++mi) {
            uint4 v = xT[(size_t)(((wq >> 4) + mi) * 2 + kk) * 64 + lane];
            afr[kk][mi] = *(bf16x8*)&v;
        }
    float Tr[8];
#pragma unroll
    for (int e = 0; e < 8; ++e) {
        int rl = wq + (e >> 2) * 16 + G * 4 + (e & 3);
        Tr[e] = Tf[rl] - qn[rl];
    }

    u32* segBase = list_seg + ((size_t)qbase * nStripsPad + (size_t)sIdx) * SEG;

    for (int s = 0; s < strip; ++s) {
        int pb = (sIdx * strip + s) * 128;
        if (pb >= N) break;

#pragma unroll
        for (int half = 0; half < 2; ++half) {
            int nb = half * 4;
            bf16x8 bfr[4][2];
#pragma unroll
            for (int j = 0; j < 4; ++j) {
                int gp = (pb >> 4) + nb + j;
#pragma unroll
                for (int kk = 0; kk < 2; ++kk) {
                    uint4 v = XT[(size_t)(gp * 2 + kk) * 64 + lane];
                    bfr[j][kk] = *(bf16x8*)&v;
                }
            }
            float xnv[4];
#pragma unroll
            for (int j = 0; j < 4; ++j) xnv[j] = Xn[pb + (nb + j) * 16 + r];

            f32x4 acc[2][4];
#pragma unroll
            for (int mi = 0; mi < 2; ++mi)
#pragma unroll
                for (int j = 0; j < 4; ++j) acc[mi][j] = (f32x4){0.f, 0.f, 0.f, 0.f};
#pragma unroll
            for (int kk = 0; kk < 2; ++kk)
#pragma unroll
                for (int j = 0; j < 4; ++j) {
                    acc[0][j] = __builtin_amdgcn_mfma_f32_16x16x32_bf16(afr[kk][0], bfr[j][kk], acc[0][j], 0, 0, 0);
                    acc[1][j] = __builtin_amdgcn_mfma_f32_16x16x32_bf16(afr[kk][1], bfr[j][kk], acc[1][j], 0, 0, 0);
                }
#pragma unroll
            for (int j = 0; j < 4; ++j) {
                int p = pb + (nb + j) * 16 + r;
                float xnp = xnv[j];
                bool c0 = fmaf(-2.f, acc[0][j][0], xnp) < Tr[0];
                bool c1 = fmaf(-2.f, acc[0][j][1], xnp) < Tr[1];
                bool c2 = fmaf(-2.f, acc[0][j][2], xnp) < Tr[2];
                bool c3 = fmaf(-2.f, acc[0][j][3], xnp) < Tr[3];
                bool c4 = fmaf(-2.f, acc[1][j][0], xnp) < Tr[4];
                bool c5 = fmaf(-2.f, acc[1][j][1], xnp) < Tr[5];
                bool c6 = fmaf(-2.f, acc[1][j][2], xnp) < Tr[6];
                bool c7 = fmaf(-2.f, acc[1][j][3], xnp) < Tr[7];
                if ((c0 | c1 | c2 | c3 | c4 | c5 | c6 | c7) && p < N) {
#pragma unroll
                    for (int e = 0; e < 8; ++e) {
                        bool ce = (e == 0) ? c0 : (e == 1) ? c1 : (e == 2) ? c2 : (e == 3) ? c3
                                : (e == 4) ? c4 : (e == 5) ? c5 : (e == 6) ? c6 : c7;
                        if (ce) {
                            int ql = w * 32 + (e >> 2) * 16 + G * 4 + (e & 3);
                            u32 slot = atomicAdd(&ldsCnt[ql], 1u);
                            if (slot < SEG) {
                                segBase[(size_t)ql * nStripsPad * SEG + slot] = (u32)p;
                            } else {
                                u32 gs = atomicAdd(&ocnt[qbase + ql], 1u);
                                if (gs < OCAP) olist[(size_t)(qbase + ql) * OCAP + gs] = (u32)p;
                            }
                        }
                    }
                }
            }
        }
    }

    __syncthreads();
    if (t < 128) cnt_seg[(size_t)(qbase + t) * nStripsPad + sIdx] = min(ldsCnt[t], (u32)SEG);
}

// ---- K3 (scalar fallback, flat list + global atomics)
__global__ __launch_bounds__(256) void k_filter_scalar(const float* __restrict__ x, const float* __restrict__ X,
                                                       const float* __restrict__ Xn, const float* __restrict__ Tq,
                                                       u32* __restrict__ cnt, u32* __restrict__ list,
                                                       int N, int cap) {
    int t = threadIdx.x;
    int q = blockIdx.x * 256 + t;
    float4 xv[16];
    float xn = load_query(x, q, xv);
    float T = Tq[q];
    int base = blockIdx.y * 1024;
    int lim = min(1024, N - base);
    for (int j = 0; j < lim; ++j) {
        int p = base + j;
        float dp = dot_row(xv, X + (size_t)p * FDIM);
        float d2 = fmaxf(xn + Xn[p] - 2.f * dp, 0.f);
        if (d2 < T) {
            u32 slot = atomicAdd(&cnt[q], 1u);
            if (slot < (u32)cap) list[(size_t)q * cap + slot] = (u32)p;
        }
    }
}

// ---- K4: gather + 8-deep-MLP coalesced rescore + rank top-32 + NN head
__global__ __launch_bounds__(256) void k_final(const float* __restrict__ x, const float* __restrict__ X,
                                               const float* __restrict__ y, const float* __restrict__ Xn,
                                               const float* __restrict__ Wg, const float* __restrict__ bg,
                                               const float* __restrict__ W1, const float* __restrict__ b1,
                                               const float* __restrict__ Wl, const float* __restrict__ bl,
                                               const u32* __restrict__ cnt_seg, const u32* __restrict__ list_seg,
                                               const u32* __restrict__ ocnt, const u32* __restrict__ olist,
                                               const u32* __restrict__ cnt_flat, const u32* __restrict__ list_flat,
                                               float* __restrict__ out, int nStripsPad, int cap_flat, int flat,
                                               int N) {
    __shared__ u64 keys[MAXCAP];
    __shared__ u32 nsh;
    __shared__ u32 sel[KNN];
    __shared__ float gkc[KNN * 16];
    __shared__ float aggc[16];
    __shared__ float red[128];

    int t = threadIdx.x;
    int w = t >> 6, lane = t & 63;
    int q = blockIdx.x;
    int m;

    if (t < KNN) sel[t] = 0;

    if (flat) {
        m = (int)min(cnt_flat[q], (u32)cap_flat);
        const u32* lq = list_flat + (size_t)q * cap_flat;
        for (int i = t; i < m; i += 256) keys[i] = lq[i];
    } else {
        if (t == 0) nsh = 0;
        __syncthreads();
        for (int seg = t; seg < nStripsPad; seg += 256) {
            u32 c = cnt_seg[(size_t)q * nStripsPad + seg];
            if (c) {
                u32 base = atomicAdd(&nsh, c);
                const u32* sp = list_seg + ((size_t)q * nStripsPad + seg) * SEG;
                for (u32 j = 0; j < c; ++j) {
                    u32 idx = base + j;
                    if (idx < MAXCAP) keys[idx] = sp[j];
                }
            }
        }
        __syncthreads();
        int m0 = (int)min(nsh, (u32)MAXCAP);
        int oc = (int)min(ocnt[q], (u32)OCAP);
        for (int i = t; i < oc; i += 256)
            if (m0 + i < MAXCAP) keys[m0 + i] = olist[(size_t)q * OCAP + i];
        m = min(m0 + oc, MAXCAP);
    }
    __syncthreads();

    // coalesced exact fp32 rescore with 8-deep load pipeline.
    // wave w owns disjoint row ranges [w*32 + 128k, w*32 + 128k + 32).
    // 16 lanes per row (ch = float4 chunk); per-row DAG identical to R8.
    {
        int ch = lane & 15;
        int rsub = lane >> 4;  // 0..3
        float4 xq4 = ((const float4*)(x + (size_t)q * FDIM))[ch];
        float xs = fmaf(xq4.x, xq4.x, fmaf(xq4.y, xq4.y, fmaf(xq4.z, xq4.z, xq4.w * xq4.w)));
        xs += __shfl_xor(xs, 1);
        xs += __shfl_xor(xs, 2);
        xs += __shfl_xor(xs, 4);
        xs += __shfl_xor(xs, 8);
        float xn = xs;
        for (int base = w * 32; base < m; base += 128) {
            int ri[8]; u32 pp[8]; bool val[8]; float4 vv[8];
#pragma unroll
            for (int u = 0; u < 8; ++u) {
                ri[u] = base + u * 4 + rsub;
                val[u] = ri[u] < m;
                pp[u] = val[u] ? (u32)keys[ri[u]] : 0u;
            }
#pragma unroll
            for (int u = 0; u < 8; ++u)
                vv[u] = ((const float4*)(X + (size_t)pp[u] * FDIM))[ch];
#pragma unroll
            for (int u = 0; u < 8; ++u) {
                float part = fmaf(xq4.x, vv[u].x, fmaf(xq4.y, vv[u].y, fmaf(xq4.z, vv[u].z, xq4.w * vv[u].w)));
                part += __shfl_xor(part, 1);
                part += __shfl_xor(part, 2);
                part += __shfl_xor(part, 4);
                part += __shfl_xor(part, 8);
                if (val[u] && ch == 0) {
                    float d2 = fmaxf(xn + Xn[pp[u]] - 2.f * part, 0.f);
                    keys[ri[u]] = ((u64)__float_as_uint(d2) << 32) | pp[u];
                }
            }
        }
    }
    __syncthreads();

    // rank-based exact top-32: unique u64 keys -> unique ranks; threads with
    // rank < KNN own a selected neighbor. One broadcast scan over m keys.
    {
        u64 mine[MAXCAP / 256];
        int rk[MAXCAP / 256];
        int nOwn = 0;
        for (int i = t; i < m; i += 256) {
            mine[nOwn] = keys[i];
            rk[nOwn] = 0;
            ++nOwn;
        }
        for (int i = 0; i < m; ++i) {
            u64 k = keys[i];
            for (int j = 0; j < nOwn; ++j) rk[j] += (k < mine[j]) ? 1 : 0;
        }
        for (int j = 0; j < nOwn; ++j)
            if (rk[j] < KNN) sel[rk[j]] = (u32)mine[j];
    }
    __syncthreads();

    int c = t & 15, kk = t >> 4;
#pragma unroll
    for (int rep = 0; rep < 2; ++rep) {
        int k = kk + 16 * rep;
        int nb = min((int)sel[k], N - 1);
        const float* Xr = X + (size_t)nb * FDIM;
        float acc = bg[c];
#pragma unroll
        for (int f = 0; f < FDIM; ++f) acc = fmaf(Xr[f], Wg[f * 16 + c], acc);
        acc = fmaf(y[nb], Wg[FDIM * 16 + c], acc);
        gkc[k * 16 + c] = tanhf(acc);
    }
    __syncthreads();
    if (t < 16) {
        float s = 0.f;
#pragma unroll
        for (int k = 0; k < KNN; ++k) s += gkc[k * 16 + t];
        aggc[t] = s;
    }
    __syncthreads();
    if (t < 128) {
        const float* xq = x + (size_t)q * FDIM;
        float acc = b1[t];
#pragma unroll
        for (int f = 0; f < FDIM; ++f) acc = fmaf(xq[f], W1[f * 128 + t], acc);
#pragma unroll
        for (int cc2 = 0; cc2 < 16; ++cc2) acc = fmaf(aggc[cc2], W1[(FDIM + cc2) * 128 + t], acc);
        red[t] = tanhf(acc) * Wl[t];
    }
    __syncthreads();
    for (int off = 64; off > 0; off >>= 1) {
        if (t < off) red[t] += red[t + off];
        __syncthreads();
    }
    if (t == 0) out[q] = 1.f / (1.f + expf(-(red[0] + bl[0])));
}

extern "C" void kernel_launch(void* const* d_in, const int* in_sizes, int n_in,
                              void* d_out, int out_size, void* d_ws, size_t ws_size,
                              hipStream_t stream) {
    const float* x  = (const float*)d_in[0];
    const float* X  = (const float*)d_in[1];
    const float* y  = (const float*)d_in[2];
    const float* Wg = (const float*)d_in[3];
    const float* bg = (const float*)d_in[4];
    const float* W1 = (const float*)d_in[5];
    const float* b1 = (const float*)d_in[6];
    const float* Wl = (const float*)d_in[7];
    const float* bl = (const float*)d_in[8];
    float* out = (float*)d_out;

    int B = in_sizes[0] / FDIM;  // 1024
    int N = in_sizes[1] / FDIM;  // 200000

    const int strip = 8;
    int nTiles = (N + 127) / 128;
    int nStrips = (nTiles + strip - 1) / strip;
    nStrips = (nStrips + 7) & ~7;
    int nStripsPad = nStrips;           // 200
    int Npad = nStrips * strip * 128;   // 204800

    char* w = (char*)d_ws;
    size_t off = 0;
    auto alloc = [&](size_t bytes) { void* p = w + off; off += (bytes + 255) & ~(size_t)255; return p; };
    float* Xn  = (float*)alloc((size_t)Npad * 4);
    float* qn  = (float*)alloc((size_t)B * 4);
    u32* hist  = (u32*)alloc((size_t)B * 512);
    float* Tq  = (float*)alloc((size_t)B * 4);
    u32* cnt   = (u32*)alloc((size_t)B * 4);

    size_t xTB = (size_t)B * 128;
    size_t XTB = (size_t)(Npad / 16) * 2048;
    size_t segCntB = (size_t)B * nStripsPad * 4;
    size_t segListB = (size_t)B * nStripsPad * SEG * 4;
    size_t ocntB = (size_t)B * 4;
    size_t olistB = (size_t)B * OCAP * 4;
    size_t rem = (ws_size > off) ? ws_size - off : 0;
    bool mfma_path = rem >= xTB + XTB + segCntB + segListB + ocntB + olistB + 4096;

    uint4* xT = nullptr; uint4* XT = nullptr;
    u32 *cnt_seg = nullptr, *list_seg = nullptr, *ocnt = nullptr, *olist = nullptr;
    u32* list_flat = nullptr; unsigned char* d2s = nullptr;
    int cap_flat = 64, Stiles = 0;
    if (mfma_path) {
        xT = (uint4*)alloc(xTB);
        XT = (uint4*)alloc(XTB);
        cnt_seg  = (u32*)alloc(segCntB);
        list_seg = (u32*)alloc(segListB);
        ocnt     = (u32*)alloc(ocntB);
        olist    = (u32*)alloc(olistB);
        rem = (ws_size > off) ? ws_size - off : 0;
        size_t st = rem / ((size_t)B * 128);
        Stiles = st > 198 ? 198 : (int)st;
        int maxFull = N / 128;
        if (Stiles > maxFull) Stiles = maxFull;
        if (Stiles >= 96) d2s = (unsigned char*)alloc((size_t)Stiles * 128 * B);
        else Stiles = 0;
    } else {
        size_t c = rem / ((size_t)B * 4);
        cap_flat = c > MAXCAP ? MAXCAP : (int)c;
        if (cap_flat < 64) cap_flat = 64;
        list_flat = (u32*)alloc((size_t)B * cap_flat * 4);
    }

    k_xnorm<<<dim3((N + 255) / 256), 256, 0, stream>>>(X, Xn, N);
    k_xnorm<<<dim3((B + 255) / 256), 256, 0, stream>>>(x, qn, B);

    if (mfma_path) {
        hipMemsetAsync(ocnt, 0, ocntB, stream);
        hipMemsetAsync(Xn + N, 0, (size_t)(Npad - N) * 4, stream);
        size_t realXT = (size_t)(N / 16) * 2048;
        hipMemsetAsync((char*)XT + realXT, 0, XTB - realXT, stream);

        int nxu4 = B * 8, nXu4 = N * 8;
        k_cvtT<<<dim3((nxu4 + 255) / 256), 256, 0, stream>>>(x, xT, nxu4);
        k_cvtT<<<dim3((nXu4 + 255) / 256), 256, 0, stream>>>(X, XT, nXu4);

        if (Stiles > 0) {
            int S = Stiles * 128;
            k_sample_d2<<<dim3(8, Stiles), 256, 0, stream>>>(xT, XT, qn, Xn, d2s, S);
            k_thresh2<<<dim3(B), 256, 0, stream>>>(d2s, Tq, S);
        } else {
            hipMemsetAsync(hist, 0, (size_t)B * 512, stream);
            int nsamp = (N + 15) / 16;
            int chunks = 128;
            int sj = (nsamp + chunks - 1) / chunks;
            k_hist<<<dim3(B / 256, chunks), 256, 0, stream>>>(x, X, Xn, hist, N, nsamp, sj);
            k_thresh<<<dim3((B + 255) / 256), 256, 0, stream>>>(hist, Tq, B);
        }

        k_mfma_filter<<<dim3(8 * nStrips), 256, 0, stream>>>(
            xT, XT, qn, Xn, Tq, cnt_seg, list_seg, ocnt, olist, N, nStripsPad, strip);

        k_final<<<dim3(B), 256, 0, stream>>>(x, X, y, Xn, Wg, bg, W1, b1, Wl, bl,
                                             cnt_seg, list_seg, ocnt, olist,
                                             nullptr, nullptr, out, nStripsPad, 0, 0, N);
    } else {
        hipMemsetAsync(cnt, 0, (size_t)B * 4, stream);
        hipMemsetAsync(hist, 0, (size_t)B * 512, stream);
        int nsamp = (N + 15) / 16;
        int chunks = 128;
        int sj = (nsamp + chunks - 1) / chunks;
        k_hist<<<dim3(B / 256, chunks), 256, 0, stream>>>(x, X, Xn, hist, N, nsamp, sj);
        k_thresh<<<dim3((B + 255) / 256), 256, 0, stream>>>(hist, Tq, B);
        k_filter_scalar<<<dim3(B / 256, (N + 1023) / 1024), 256, 0, stream>>>(
            x, X, Xn, Tq, cnt, list_flat, N, cap_flat);
        k_final<<<dim3(B), 256, 0, stream>>>(x, X, y, Xn, Wg, bg, W1, b1, Wl, bl,
                                             nullptr, nullptr, nullptr, nullptr,
                                             cnt, list_flat, out, nStripsPad, cap_flat, 1, N);
    }
}

// Round 10
// 287.404 us; speedup vs baseline: 2.1149x; 2.1149x over previous
//
#include <hip/hip_runtime.h>
#include <cstdint>

#define FDIM 64
#define KNN 32
#define NBUCKET 256
#define MAXCAP 2048
#define SEG 10
#define OCAP 512

typedef unsigned int u32;
typedef unsigned long long u64;
typedef __attribute__((ext_vector_type(8))) short bf16x8;
typedef __attribute__((ext_vector_type(4))) float f32x4;

// ---- shared fp32 helpers
__device__ __forceinline__ float load_query(const float* __restrict__ x, int q, float4* xv) {
    const float4* xp = (const float4*)(x + (size_t)q * FDIM);
    float n0 = 0.f, n1 = 0.f, n2 = 0.f, n3 = 0.f;
#pragma unroll
    for (int k = 0; k < 16; ++k) {
        float4 v = xp[k];
        xv[k] = v;
        n0 = fmaf(v.x, v.x, n0); n1 = fmaf(v.y, v.y, n1);
        n2 = fmaf(v.z, v.z, n2); n3 = fmaf(v.w, v.w, n3);
    }
    return (n0 + n1) + (n2 + n3);
}

__device__ __forceinline__ float dot_row(const float4* __restrict__ xv, const float* __restrict__ row) {
    const float4* rv = (const float4*)row;
    float d0 = 0.f, d1 = 0.f, d2 = 0.f, d3 = 0.f;
#pragma unroll
    for (int k = 0; k < 16; ++k) {
        float4 r = rv[k];
        float4 a = xv[k];
        d0 = fmaf(a.x, r.x, d0); d1 = fmaf(a.y, r.y, d1);
        d2 = fmaf(a.z, r.z, d2); d3 = fmaf(a.w, r.w, d3);
    }
    return (d0 + d1) + (d2 + d3);
}

// ---- K1: row norms
__global__ __launch_bounds__(256) void k_xnorm(const float* __restrict__ X, float* __restrict__ Xn, int N) {
    int i = blockIdx.x * 256 + threadIdx.x;
    if (i >= N) return;
    const float4* r = (const float4*)(X + (size_t)i * FDIM);
    float d0 = 0.f, d1 = 0.f, d2 = 0.f, d3 = 0.f;
#pragma unroll
    for (int k = 0; k < 16; ++k) {
        float4 v = r[k];
        d0 = fmaf(v.x, v.x, d0); d1 = fmaf(v.y, v.y, d1);
        d2 = fmaf(v.z, v.z, d2); d3 = fmaf(v.w, v.w, d3);
    }
    Xn[i] = (d0 + d1) + (d2 + d3);
}

// ---- K1b: fused fp32->bf16 (RNE) + transpose into MFMA-fragment order.
__global__ __launch_bounds__(256) void k_cvtT(const float* __restrict__ src, uint4* __restrict__ dst, int n_u4) {
    int i = blockIdx.x * 256 + threadIdx.x;
    if (i >= n_u4) return;
    int lane = i & 63;
    int kk = (i >> 6) & 1;
    int g = i >> 7;
    int row = g * 16 + (lane & 15);
    int col = kk * 32 + (lane >> 4) * 8;
    const float4* s = (const float4*)(src + (size_t)row * FDIM + col);
    float4 a = s[0], b = s[1];
    ushort o[8];
    const float* f = &a.x;
#pragma unroll
    for (int k = 0; k < 4; ++k) {
        u32 u = __float_as_uint(f[k]);
        o[k] = (ushort)((u + 0x7fffu + ((u >> 16) & 1u)) >> 16);
    }
    const float* gg = &b.x;
#pragma unroll
    for (int k = 0; k < 4; ++k) {
        u32 u = __float_as_uint(gg[k]);
        o[4 + k] = (ushort)((u + 0x7fffu + ((u >> 16) & 1u)) >> 16);
    }
    dst[i] = *(uint4*)o;
}

// ---- legacy scalar sample-hist kernels (fallback when ws is tight) ----
__global__ __launch_bounds__(256) void k_hist(const float* __restrict__ x, const float* __restrict__ X,
                                              const float* __restrict__ Xn, u32* __restrict__ hist,
                                              int N, int nsamp, int sj) {
    __shared__ unsigned char h8[NBUCKET * 256];
    int t = threadIdx.x;
    u32* h32 = (u32*)h8;
#pragma unroll
    for (int k = 0; k < 64; ++k) h32[k * 256 + t] = 0;
    __syncthreads();
    int q = blockIdx.x * 256 + t;
    float4 xv[16];
    float xn = load_query(x, q, xv);
    for (int j = 0; j < sj; ++j) {
        int s = blockIdx.y * sj + j;
        int p = s * 16;
        if (s < nsamp && p < N) {
            float dp = dot_row(xv, X + (size_t)p * FDIM);
            float d2 = fmaxf(xn + Xn[p] - 2.f * dp, 0.f);
            int b = min(NBUCKET - 1, (int)d2);
            int idx = b * 256 + t;
            unsigned char v = h8[idx];
            h8[idx] = (v == 255u) ? v : (unsigned char)(v + 1);
        }
    }
    __syncthreads();
#pragma unroll
    for (int w = 0; w < 128; ++w) {
        u32 v0 = h8[(2 * w) * 256 + t];
        u32 v1 = h8[(2 * w + 1) * 256 + t];
        if (v0 | v1) atomicAdd(&hist[(size_t)q * 128 + w], v0 | (v1 << 16));
    }
}

__global__ __launch_bounds__(256) void k_thresh(const u32* __restrict__ hist, float* __restrict__ Tq, int B) {
    int q = blockIdx.x * 256 + threadIdx.x;
    if (q >= B) return;
    const u32* h = hist + (size_t)q * 128;
    int cum = 0;
    float T = (float)NBUCKET;
    for (int w = 0; w < 128; ++w) {
        u32 v = h[w];
        cum += (int)(v & 0xffffu);
        if (cum >= KNN) { T = (float)(2 * w + 1); break; }
        cum += (int)(v >> 16);
        if (cum >= KNN) { T = (float)(2 * w + 2); break; }
    }
    Tq[q] = T + 2.0f;
}

// ---- K2 (MFMA sample pass): d2a buckets for the first S=Stiles*128 rows.
__global__ __launch_bounds__(256, 3) void k_sample_d2(
        const uint4* __restrict__ xT, const uint4* __restrict__ XT,
        const float* __restrict__ qn, const float* __restrict__ Xn,
        unsigned char* __restrict__ d2s, int S) {
    int t = threadIdx.x;
    int w = t >> 6, lane = t & 63;
    int G = lane >> 4, r = lane & 15;
    int qg = blockIdx.x;
    int wq = qg * 128 + w * 32;
    int pb = blockIdx.y * 128;

    bf16x8 afr[2][2];
#pragma unroll
    for (int kk = 0; kk < 2; ++kk)
#pragma unroll
        for (int mi = 0; mi < 2; ++mi) {
            uint4 v = xT[(size_t)(((wq >> 4) + mi) * 2 + kk) * 64 + lane];
            afr[kk][mi] = *(bf16x8*)&v;
        }
    float qr[8];
#pragma unroll
    for (int e = 0; e < 8; ++e)
        qr[e] = qn[wq + (e >> 2) * 16 + G * 4 + (e & 3)];

#pragma unroll
    for (int half = 0; half < 2; ++half) {
        int nb = half * 4;
        bf16x8 bfr[4][2];
#pragma unroll
        for (int j = 0; j < 4; ++j) {
            int gp = (pb >> 4) + nb + j;
#pragma unroll
            for (int kk = 0; kk < 2; ++kk) {
                uint4 v = XT[(size_t)(gp * 2 + kk) * 64 + lane];
                bfr[j][kk] = *(bf16x8*)&v;
            }
        }
        float xnv[4];
#pragma unroll
        for (int j = 0; j < 4; ++j) xnv[j] = Xn[pb + (nb + j) * 16 + r];

        f32x4 acc[2][4];
#pragma unroll
        for (int mi = 0; mi < 2; ++mi)
#pragma unroll
            for (int j = 0; j < 4; ++j) acc[mi][j] = (f32x4){0.f, 0.f, 0.f, 0.f};
#pragma unroll
        for (int kk = 0; kk < 2; ++kk)
#pragma unroll
            for (int j = 0; j < 4; ++j) {
                acc[0][j] = __builtin_amdgcn_mfma_f32_16x16x32_bf16(afr[kk][0], bfr[j][kk], acc[0][j], 0, 0, 0);
                acc[1][j] = __builtin_amdgcn_mfma_f32_16x16x32_bf16(afr[kk][1], bfr[j][kk], acc[1][j], 0, 0, 0);
            }
#pragma unroll
        for (int j = 0; j < 4; ++j) {
            int p = pb + (nb + j) * 16 + r;
            float xnp = xnv[j];
#pragma unroll
            for (int e = 0; e < 8; ++e) {
                float d2a = qr[e] + fmaf(-2.f, acc[e >> 2][j][e & 3], xnp);
                int b = (int)d2a;
                b = b < 0 ? 0 : (b > 255 ? 255 : b);
                int q = wq + (e >> 2) * 16 + G * 4 + (e & 3);
                d2s[(size_t)q * S + p] = (unsigned char)b;
            }
        }
    }
}

// ---- K2b: per-query hist of d2a bytes -> threshold + 2eps margin (eps=1.0)
__global__ __launch_bounds__(256) void k_thresh2(const unsigned char* __restrict__ d2s,
                                                 float* __restrict__ Tq, int S) {
    __shared__ u32 h[NBUCKET];
    int t = threadIdx.x;
    int q = blockIdx.x;
    h[t] = 0;
    __syncthreads();
    const u32* row = (const u32*)(d2s + (size_t)q * S);
    int n4 = S >> 2;
    for (int i = t; i < n4; i += 256) {
        u32 v = row[i];
        atomicAdd(&h[v & 255u], 1u);
        atomicAdd(&h[(v >> 8) & 255u], 1u);
        atomicAdd(&h[(v >> 16) & 255u], 1u);
        atomicAdd(&h[v >> 24], 1u);
    }
    __syncthreads();
    if (t == 0) {
        int cum = 0;
        float T = 256.0f;
        for (int b = 0; b < NBUCKET; ++b) {
            cum += (int)h[b];
            if (cum >= KNN) { T = (float)(b + 1); break; }
        }
        Tq[q] = T + 2.0f;
    }
}

// ---- K3: LDS-free MFMA filter; per-(q,strip) segments via LDS atomics
__global__ __launch_bounds__(256, 3) void k_mfma_filter(
        const uint4* __restrict__ xT, const uint4* __restrict__ XT,
        const float* __restrict__ qn, const float* __restrict__ Xn,
        const float* __restrict__ Tf,
        u32* __restrict__ cnt_seg, u32* __restrict__ list_seg,
        u32* __restrict__ ocnt, u32* __restrict__ olist,
        int N, int nStripsPad, int strip) {
    __shared__ u32 ldsCnt[128];

    int t = threadIdx.x;
    int w = t >> 6, lane = t & 63;
    int G = lane >> 4, r = lane & 15;

    int bid = blockIdx.x;
    int qg = (bid >> 3) & 7;
    int sIdx = (bid & 7) | ((bid >> 6) << 3);
    int qbase = qg * 128;
    int wq = qbase + w * 32;

    if (t < 128) ldsCnt[t] = 0;
    __syncthreads();

    bf16x8 afr[2][2];
#pragma unroll
    for (int kk = 0; kk < 2; ++kk)
#pragma unroll
        for (int mi = 0; mi < 2; ++mi) {
            uint4 v = xT[(size_t)(((wq >> 4) + mi) * 2 + kk) * 64 + lane];
            afr[kk][mi] = *(bf16x8*)&v;
        }
    float Tr[8];
#pragma unroll
    for (int e = 0; e < 8; ++e) {
        int rl = wq + (e >> 2) * 16 + G * 4 + (e & 3);
        Tr[e] = Tf[rl] - qn[rl];
    }

    u32* segBase = list_seg + ((size_t)qbase * nStripsPad + (size_t)sIdx) * SEG;

    for (int s = 0; s < strip; ++s) {
        int pb = (sIdx * strip + s) * 128;
        if (pb >= N) break;

#pragma unroll
        for (int half = 0; half < 2; ++half) {
            int nb = half * 4;
            bf16x8 bfr[4][2];
#pragma unroll
            for (int j = 0; j < 4; ++j) {
                int gp = (pb >> 4) + nb + j;
#pragma unroll
                for (int kk = 0; kk < 2; ++kk) {
                    uint4 v = XT[(size_t)(gp * 2 + kk) * 64 + lane];
                    bfr[j][kk] = *(bf16x8*)&v;
                }
            }
            float xnv[4];
#pragma unroll
            for (int j = 0; j < 4; ++j) xnv[j] = Xn[pb + (nb + j) * 16 + r];

            f32x4 acc[2][4];
#pragma unroll
            for (int mi = 0; mi < 2; ++mi)
#pragma unroll
                for (int j = 0; j < 4; ++j) acc[mi][j] = (f32x4){0.f, 0.f, 0.f, 0.f};
#pragma unroll
            for (int kk = 0; kk < 2; ++kk)
#pragma unroll
                for (int j = 0; j < 4; ++j) {
                    acc[0][j] = __builtin_amdgcn_mfma_f32_16x16x32_bf16(afr[kk][0], bfr[j][kk], acc[0][j], 0, 0, 0);
                    acc[1][j] = __builtin_amdgcn_mfma_f32_16x16x32_bf16(afr[kk][1], bfr[j][kk], acc[1][j], 0, 0, 0);
                }
#pragma unroll
            for (int j = 0; j < 4; ++j) {
                int p = pb + (nb + j) * 16 + r;
                float xnp = xnv[j];
                bool c0 = fmaf(-2.f, acc[0][j][0], xnp) < Tr[0];
                bool c1 = fmaf(-2.f, acc[0][j][1], xnp) < Tr[1];
                bool c2 = fmaf(-2.f, acc[0][j][2], xnp) < Tr[2];
                bool c3 = fmaf(-2.f, acc[0][j][3], xnp) < Tr[3];
                bool c4 = fmaf(-2.f, acc[1][j][0], xnp) < Tr[4];
                bool c5 = fmaf(-2.f, acc[1][j][1], xnp) < Tr[5];
                bool c6 = fmaf(-2.f, acc[1][j][2], xnp) < Tr[6];
                bool c7 = fmaf(-2.f, acc[1][j][3], xnp) < Tr[7];
                if ((c0 | c1 | c2 | c3 | c4 | c5 | c6 | c7) && p < N) {
#pragma unroll
                    for (int e = 0; e < 8; ++e) {
                        bool ce = (e == 0) ? c0 : (e == 1) ? c1 : (e == 2) ? c2 : (e == 3) ? c3
                                : (e == 4) ? c4 : (e == 5) ? c5 : (e == 6) ? c6 : c7;
                        if (ce) {
                            int ql = w * 32 + (e >> 2) * 16 + G * 4 + (e & 3);
                            u32 slot = atomicAdd(&ldsCnt[ql], 1u);
                            if (slot < SEG) {
                                segBase[(size_t)ql * nStripsPad * SEG + slot] = (u32)p;
                            } else {
                                u32 gs = atomicAdd(&ocnt[qbase + ql], 1u);
                                if (gs < OCAP) olist[(size_t)(qbase + ql) * OCAP + gs] = (u32)p;
                            }
                        }
                    }
                }
            }
        }
    }

    __syncthreads();
    if (t < 128) cnt_seg[(size_t)(qbase + t) * nStripsPad + sIdx] = min(ldsCnt[t], (u32)SEG);
}

// ---- K3 (scalar fallback, flat list + global atomics)
__global__ __launch_bounds__(256) void k_filter_scalar(const float* __restrict__ x, const float* __restrict__ X,
                                                       const float* __restrict__ Xn, const float* __restrict__ Tq,
                                                       u32* __restrict__ cnt, u32* __restrict__ list,
                                                       int N, int cap) {
    int t = threadIdx.x;
    int q = blockIdx.x * 256 + t;
    float4 xv[16];
    float xn = load_query(x, q, xv);
    float T = Tq[q];
    int base = blockIdx.y * 1024;
    int lim = min(1024, N - base);
    for (int j = 0; j < lim; ++j) {
        int p = base + j;
        float dp = dot_row(xv, X + (size_t)p * FDIM);
        float d2 = fmaxf(xn + Xn[p] - 2.f * dp, 0.f);
        if (d2 < T) {
            u32 slot = atomicAdd(&cnt[q], 1u);
            if (slot < (u32)cap) list[(size_t)q * cap + slot] = (u32)p;
        }
    }
}

// ---- K4: gather + 8-deep pipelined coalesced rescore + wave-0 butterfly top-32 + NN head
__global__ __launch_bounds__(256) void k_final(const float* __restrict__ x, const float* __restrict__ X,
                                               const float* __restrict__ y, const float* __restrict__ Xn,
                                               const float* __restrict__ Wg, const float* __restrict__ bg,
                                               const float* __restrict__ W1, const float* __restrict__ b1,
                                               const float* __restrict__ Wl, const float* __restrict__ bl,
                                               const u32* __restrict__ cnt_seg, const u32* __restrict__ list_seg,
                                               const u32* __restrict__ ocnt, const u32* __restrict__ olist,
                                               const u32* __restrict__ cnt_flat, const u32* __restrict__ list_flat,
                                               float* __restrict__ out, int nStripsPad, int cap_flat, int flat,
                                               int N) {
    __shared__ u64 keys[MAXCAP];
    __shared__ u32 nsh;
    __shared__ u64 wk[4];
    __shared__ int wp[4];
    __shared__ u32 sel[KNN];
    __shared__ float gkc[KNN * 16];
    __shared__ float aggc[16];
    __shared__ float red[128];

    int t = threadIdx.x;
    int w = t >> 6, lane = t & 63;
    int q = blockIdx.x;
    int m;

    if (flat) {
        m = (int)min(cnt_flat[q], (u32)cap_flat);
        const u32* lq = list_flat + (size_t)q * cap_flat;
        for (int i = t; i < m; i += 256) keys[i] = lq[i];
    } else {
        if (t == 0) nsh = 0;
        __syncthreads();
        for (int seg = t; seg < nStripsPad; seg += 256) {
            u32 c = cnt_seg[(size_t)q * nStripsPad + seg];
            if (c) {
                u32 base = atomicAdd(&nsh, c);
                const u32* sp = list_seg + ((size_t)q * nStripsPad + seg) * SEG;
                for (u32 j = 0; j < c; ++j) {
                    u32 idx = base + j;
                    if (idx < MAXCAP) keys[idx] = sp[j];
                }
            }
        }
        __syncthreads();
        int m0 = (int)min(nsh, (u32)MAXCAP);
        int oc = (int)min(ocnt[q], (u32)OCAP);
        for (int i = t; i < oc; i += 256)
            if (m0 + i < MAXCAP) keys[m0 + i] = olist[(size_t)q * OCAP + i];
        m = min(m0 + oc, MAXCAP);
    }
    __syncthreads();

    // coalesced exact fp32 rescore with 8-deep load pipeline.
    // wave w owns disjoint row ranges [w*32 + 128k, w*32 + 128k + 32).
    // 16 lanes per row (ch = float4 chunk); per-row DAG identical to R8.
    {
        int ch = lane & 15;
        int rsub = lane >> 4;  // 0..3
        float4 xq4 = ((const float4*)(x + (size_t)q * FDIM))[ch];
        float xs = fmaf(xq4.x, xq4.x, fmaf(xq4.y, xq4.y, fmaf(xq4.z, xq4.z, xq4.w * xq4.w)));
        xs += __shfl_xor(xs, 1);
        xs += __shfl_xor(xs, 2);
        xs += __shfl_xor(xs, 4);
        xs += __shfl_xor(xs, 8);
        float xn = xs;
        for (int base = w * 32; base < m; base += 128) {
            int ri[8]; u32 pp[8]; bool val[8]; float4 vv[8];
#pragma unroll
            for (int u = 0; u < 8; ++u) {
                ri[u] = base + u * 4 + rsub;
                val[u] = ri[u] < m;
                pp[u] = val[u] ? (u32)keys[ri[u]] : 0u;
            }
#pragma unroll
            for (int u = 0; u < 8; ++u)
                vv[u] = ((const float4*)(X + (size_t)pp[u] * FDIM))[ch];
#pragma unroll
            for (int u = 0; u < 8; ++u) {
                float part = fmaf(xq4.x, vv[u].x, fmaf(xq4.y, vv[u].y, fmaf(xq4.z, vv[u].z, xq4.w * vv[u].w)));
                part += __shfl_xor(part, 1);
                part += __shfl_xor(part, 2);
                part += __shfl_xor(part, 4);
                part += __shfl_xor(part, 8);
                if (val[u] && ch == 0) {
                    float d2 = fmaxf(xn + Xn[pp[u]] - 2.f * part, 0.f);
                    keys[ri[u]] = ((u64)__float_as_uint(d2) << 32) | pp[u];
                }
            }
        }
    }
    __syncthreads();

    if (m <= 512) {
        // barrier-free selection in wave 0's registers (R7/R8 proven)
        if (w == 0) {
            u64 rk[8];
#pragma unroll
            for (int i = 0; i < 8; ++i) {
                int idx = lane + (i << 6);
                rk[i] = (idx < m) ? keys[idx] : ~0ull;
            }
            for (int r = 0; r < KNN; ++r) {
                u64 bk = ~0ull;
                int bs = 0;
#pragma unroll
                for (int i = 0; i < 8; ++i)
                    if (rk[i] < bk) { bk = rk[i]; bs = i; }
                int bo = lane;
#pragma unroll
                for (int off = 1; off < 64; off <<= 1) {
                    u64 ok = __shfl_xor(bk, off);
                    int oo = __shfl_xor(bo, off);
                    if (ok < bk) { bk = ok; bo = oo; }
                }
                if (lane == bo) rk[bs] = ~0ull;
                if (lane == 0) sel[r] = (u32)bk;
            }
        }
        __syncthreads();
    } else {
        for (int r = 0; r < KNN; ++r) {
            u64 bk = ~0ull;
            int bp = -1;
            for (int i = t; i < m; i += 256) {
                u64 k = keys[i];
                if (k < bk) { bk = k; bp = i; }
            }
#pragma unroll
            for (int off = 32; off > 0; off >>= 1) {
                u64 ok = __shfl_down(bk, off);
                int op = __shfl_down(bp, off);
                if (ok < bk) { bk = ok; bp = op; }
            }
            if (lane == 0) { wk[w] = bk; wp[w] = bp; }
            __syncthreads();
            if (t == 0) {
                u64 fb = wk[0];
                int fp = wp[0];
                for (int v = 1; v < 4; ++v)
                    if (wk[v] < fb) { fb = wk[v]; fp = wp[v]; }
                sel[r] = (u32)(fb & 0xffffffffu);
                if (fp >= 0) keys[fp] = ~0ull;
            }
            __syncthreads();
        }
    }

    int c = t & 15, kk = t >> 4;
#pragma unroll
    for (int rep = 0; rep < 2; ++rep) {
        int k = kk + 16 * rep;
        int nb = min((int)sel[k], N - 1);
        const float* Xr = X + (size_t)nb * FDIM;
        float acc = bg[c];
#pragma unroll
        for (int f = 0; f < FDIM; ++f) acc = fmaf(Xr[f], Wg[f * 16 + c], acc);
        acc = fmaf(y[nb], Wg[FDIM * 16 + c], acc);
        gkc[k * 16 + c] = tanhf(acc);
    }
    __syncthreads();
    if (t < 16) {
        float s = 0.f;
#pragma unroll
        for (int k = 0; k < KNN; ++k) s += gkc[k * 16 + t];
        aggc[t] = s;
    }
    __syncthreads();
    if (t < 128) {
        const float* xq = x + (size_t)q * FDIM;
        float acc = b1[t];
#pragma unroll
        for (int f = 0; f < FDIM; ++f) acc = fmaf(xq[f], W1[f * 128 + t], acc);
#pragma unroll
        for (int cc2 = 0; cc2 < 16; ++cc2) acc = fmaf(aggc[cc2], W1[(FDIM + cc2) * 128 + t], acc);
        red[t] = tanhf(acc) * Wl[t];
    }
    __syncthreads();
    for (int off = 64; off > 0; off >>= 1) {
        if (t < off) red[t] += red[t + off];
        __syncthreads();
    }
    if (t == 0) out[q] = 1.f / (1.f + expf(-(red[0] + bl[0])));
}

extern "C" void kernel_launch(void* const* d_in, const int* in_sizes, int n_in,
                              void* d_out, int out_size, void* d_ws, size_t ws_size,
                              hipStream_t stream) {
    const float* x  = (const float*)d_in[0];
    const float* X  = (const float*)d_in[1];
    const float* y  = (const float*)d_in[2];
    const float* Wg = (const float*)d_in[3];
    const float* bg = (const float*)d_in[4];
    const float* W1 = (const float*)d_in[5];
    const float* b1 = (const float*)d_in[6];
    const float* Wl = (const float*)d_in[7];
    const float* bl = (const float*)d_in[8];
    float* out = (float*)d_out;

    int B = in_sizes[0] / FDIM;  // 1024
    int N = in_sizes[1] / FDIM;  // 200000

    const int strip = 8;
    int nTiles = (N + 127) / 128;
    int nStrips = (nTiles + strip - 1) / strip;
    nStrips = (nStrips + 7) & ~7;
    int nStripsPad = nStrips;           // 200
    int Npad = nStrips * strip * 128;   // 204800

    char* w = (char*)d_ws;
    size_t off = 0;
    auto alloc = [&](size_t bytes) { void* p = w + off; off += (bytes + 255) & ~(size_t)255; return p; };
    float* Xn  = (float*)alloc((size_t)Npad * 4);
    float* qn  = (float*)alloc((size_t)B * 4);
    u32* hist  = (u32*)alloc((size_t)B * 512);
    float* Tq  = (float*)alloc((size_t)B * 4);
    u32* cnt   = (u32*)alloc((size_t)B * 4);

    size_t xTB = (size_t)B * 128;
    size_t XTB = (size_t)(Npad / 16) * 2048;
    size_t segCntB = (size_t)B * nStripsPad * 4;
    size_t segListB = (size_t)B * nStripsPad * SEG * 4;
    size_t ocntB = (size_t)B * 4;
    size_t olistB = (size_t)B * OCAP * 4;
    size_t rem = (ws_size > off) ? ws_size - off : 0;
    bool mfma_path = rem >= xTB + XTB + segCntB + segListB + ocntB + olistB + 4096;

    uint4* xT = nullptr; uint4* XT = nullptr;
    u32 *cnt_seg = nullptr, *list_seg = nullptr, *ocnt = nullptr, *olist = nullptr;
    u32* list_flat = nullptr; unsigned char* d2s = nullptr;
    int cap_flat = 64, Stiles = 0;
    if (mfma_path) {
        xT = (uint4*)alloc(xTB);
        XT = (uint4*)alloc(XTB);
        cnt_seg  = (u32*)alloc(segCntB);
        list_seg = (u32*)alloc(segListB);
        ocnt     = (u32*)alloc(ocntB);
        olist    = (u32*)alloc(olistB);
        rem = (ws_size > off) ? ws_size - off : 0;
        size_t st = rem / ((size_t)B * 128);
        Stiles = st > 198 ? 198 : (int)st;
        int maxFull = N / 128;
        if (Stiles > maxFull) Stiles = maxFull;
        if (Stiles >= 96) d2s = (unsigned char*)alloc((size_t)Stiles * 128 * B);
        else Stiles = 0;
    } else {
        size_t c = rem / ((size_t)B * 4);
        cap_flat = c > MAXCAP ? MAXCAP : (int)c;
        if (cap_flat < 64) cap_flat = 64;
        list_flat = (u32*)alloc((size_t)B * cap_flat * 4);
    }

    k_xnorm<<<dim3((N + 255) / 256), 256, 0, stream>>>(X, Xn, N);
    k_xnorm<<<dim3((B + 255) / 256), 256, 0, stream>>>(x, qn, B);

    if (mfma_path) {
        hipMemsetAsync(ocnt, 0, ocntB, stream);
        hipMemsetAsync(Xn + N, 0, (size_t)(Npad - N) * 4, stream);
        size_t realXT = (size_t)(N / 16) * 2048;
        hipMemsetAsync((char*)XT + realXT, 0, XTB - realXT, stream);

        int nxu4 = B * 8, nXu4 = N * 8;
        k_cvtT<<<dim3((nxu4 + 255) / 256), 256, 0, stream>>>(x, xT, nxu4);
        k_cvtT<<<dim3((nXu4 + 255) / 256), 256, 0, stream>>>(X, XT, nXu4);

        if (Stiles > 0) {
            int S = Stiles * 128;
            k_sample_d2<<<dim3(8, Stiles), 256, 0, stream>>>(xT, XT, qn, Xn, d2s, S);
            k_thresh2<<<dim3(B), 256, 0, stream>>>(d2s, Tq, S);
        } else {
            hipMemsetAsync(hist, 0, (size_t)B * 512, stream);
            int nsamp = (N + 15) / 16;
            int chunks = 128;
            int sj = (nsamp + chunks - 1) / chunks;
            k_hist<<<dim3(B / 256, chunks), 256, 0, stream>>>(x, X, Xn, hist, N, nsamp, sj);
            k_thresh<<<dim3((B + 255) / 256), 256, 0, stream>>>(hist, Tq, B);
        }

        k_mfma_filter<<<dim3(8 * nStrips), 256, 0, stream>>>(
            xT, XT, qn, Xn, Tq, cnt_seg, list_seg, ocnt, olist, N, nStripsPad, strip);

        k_final<<<dim3(B), 256, 0, stream>>>(x, X, y, Xn, Wg, bg, W1, b1, Wl, bl,
                                             cnt_seg, list_seg, ocnt, olist,
                                             nullptr, nullptr, out, nStripsPad, 0, 0, N);
    } else {
        hipMemsetAsync(cnt, 0, (size_t)B * 4, stream);
        hipMemsetAsync(hist, 0, (size_t)B * 512, stream);
        int nsamp = (N + 15) / 16;
        int chunks = 128;
        int sj = (nsamp + chunks - 1) / chunks;
        k_hist<<<dim3(B / 256, chunks), 256, 0, stream>>>(x, X, Xn, hist, N, nsamp, sj);
        k_thresh<<<dim3((B + 255) / 256), 256, 0, stream>>>(hist, Tq, B);
        k_filter_scalar<<<dim3(B / 256, (N + 1023) / 1024), 256, 0, stream>>>(
            x, X, Xn, Tq, cnt, list_flat, N, cap_flat);
        k_final<<<dim3(B), 256, 0, stream>>>(x, X, y, Xn, Wg, bg, W1, b1, Wl, bl,
                                             nullptr, nullptr, nullptr, nullptr,
                                             cnt, list_flat, out, nStripsPad, cap_flat, 1, N);
    }
}